// Round 14
// baseline (180.138 us; speedup 1.0000x reference)
//
#include <hip/hip_runtime.h>

// CausalWanSelfAttention: DIM=1024, 64 heads of head-dim 1, N=2048.
// out[i,c] = sum_h w_out[c,h] * softmax_j<=i( q[i,h]*k[j,h]/8 ) . v[j,h]
//
// ===== ROUND 13 (resubmit): ATTRIBUTION ROUND =====
// Identical to R12 except attn_kernel repeats its compute `reps`(=4) times
// (stage once, compute x4, idempotent stores). Purpose: (a) dur_us delta
// = 3*t_attn measures attn exactly; (b) the inflated dispatch (4*t_attn)
// enters the rocprof top-5 past the harness's ~44us ws-poison fills,
// giving attn's own counters for the first time since R2.
// asm volatile("" : "+v"(q)) per rep prevents cross-rep CSE (guide rule #17).

#if __has_builtin(__builtin_amdgcn_exp2f)
#define EXP2F(x) __builtin_amdgcn_exp2f(x)
#else
#define EXP2F(x) exp2f(x)
#endif

#define LOG2E_DIV8 0.18033688011112042f  // log2(e)/8

// grid 64: b<48 -> 64x64 tile of wqkv[192][1024] -> wT[1024][192] (scaled rows);
//          b>=48 -> 64x64 tile of wout[1024][64] -> wOutT[64][1024]
__global__ __launch_bounds__(256) void prep_kernel(const float* __restrict__ wqkv,
                                                   const float* __restrict__ wout,
                                                   float* __restrict__ wT,
                                                   float* __restrict__ wOutT) {
    __shared__ float tile[64][65];
    const int t = threadIdx.x;
    const int b = blockIdx.x;
    const int r = t & 63;
    const int g = t >> 6;     // 0..3
    if (b < 48) {
        const int f0 = (b % 3) * 64;
        const int k0 = (b / 3) * 64;
#pragma unroll
        for (int j = 0; j < 4; ++j) {
            float4 v = *(const float4*)(wqkv + (size_t)(f0 + r) * 1024 + k0 + g * 16 + j * 4);
            tile[r][g * 16 + j * 4 + 0] = v.x;
            tile[r][g * 16 + j * 4 + 1] = v.y;
            tile[r][g * 16 + j * 4 + 2] = v.z;
            tile[r][g * 16 + j * 4 + 3] = v.w;
        }
        __syncthreads();
        const float sc = (f0 == 64) ? LOG2E_DIV8 : 1.0f;  // k-features f in [64,128)
#pragma unroll
        for (int j = 0; j < 16; ++j) {
            const int k = k0 + g * 16 + j;
            wT[(size_t)k * 192 + f0 + r] = tile[r][g * 16 + j] * sc;
        }
    } else {
        const int c0 = (b - 48) * 64;
#pragma unroll
        for (int j = 0; j < 4; ++j) {
            float4 v = *(const float4*)(wout + (size_t)(c0 + r) * 64 + g * 16 + j * 4);
            tile[r][g * 16 + j * 4 + 0] = v.x;
            tile[r][g * 16 + j * 4 + 1] = v.y;
            tile[r][g * 16 + j * 4 + 2] = v.z;
            tile[r][g * 16 + j * 4 + 3] = v.w;
        }
        __syncthreads();
#pragma unroll
        for (int j = 0; j < 16; ++j) {
            const int h = g * 16 + j;
            wOutT[(size_t)h * 1024 + c0 + r] = tile[r][h];
        }
    }
}

// C[2048][192] = x[2048][1024] * wT[1024][192], split-K=16 (K=64 per block).
// grid 768 = 16 mtiles(128) * 3 ntiles(64) * 16 ksplit; block 256; micro 8x4.
__global__ __launch_bounds__(256) void qkv_gemm(const float* __restrict__ x,
                                                const float* __restrict__ wT,
                                                float* __restrict__ pq) {
    __shared__ float xsT[32][128];  // [k][row]
    __shared__ float wsld[32][64];  // [k][f]
    const int t = threadIdx.x;
    const int b = blockIdx.x;
    const int ks = b & 15;
    const int nt = (b >> 4) % 3;
    const int mt = b / 48;
    const int i0 = mt * 128;
    const int cb = nt * 64;
    const int k0 = ks * 64;

    const int xr = t & 127;   // x staging row
    const int xq = t >> 7;    // 0..1 -> 16 k each
    const int wf = t & 63;    // w staging f
    const int wq = t >> 6;    // 0..3 -> 8 k each
    const int tx = t & 15;
    const int ty = t >> 4;

    const float* xp = x + (size_t)(i0 + xr) * 1024 + k0 + xq * 16;
    const float* wp = wT + (size_t)(k0 + wq * 8) * 192 + cb + wf;

    float4 xa0 = *(const float4*)(xp);
    float4 xa1 = *(const float4*)(xp + 4);
    float4 xa2 = *(const float4*)(xp + 8);
    float4 xa3 = *(const float4*)(xp + 12);
    float wr[8];
#pragma unroll
    for (int j = 0; j < 8; ++j) wr[j] = wp[(size_t)j * 192];

    float acc[8][4] = {};

    for (int s = 0; s < 2; ++s) {
        __syncthreads();
        {
            const int kb = xq * 16;
            xsT[kb + 0][xr] = xa0.x; xsT[kb + 1][xr] = xa0.y;
            xsT[kb + 2][xr] = xa0.z; xsT[kb + 3][xr] = xa0.w;
            xsT[kb + 4][xr] = xa1.x; xsT[kb + 5][xr] = xa1.y;
            xsT[kb + 6][xr] = xa1.z; xsT[kb + 7][xr] = xa1.w;
            xsT[kb + 8][xr] = xa2.x; xsT[kb + 9][xr] = xa2.y;
            xsT[kb + 10][xr] = xa2.z; xsT[kb + 11][xr] = xa2.w;
            xsT[kb + 12][xr] = xa3.x; xsT[kb + 13][xr] = xa3.y;
            xsT[kb + 14][xr] = xa3.z; xsT[kb + 15][xr] = xa3.w;
            const int kw = wq * 8;
#pragma unroll
            for (int j = 0; j < 8; ++j) wsld[kw + j][wf] = wr[j];
        }
        __syncthreads();
        if (s == 0) {
            xa0 = *(const float4*)(xp + 32);
            xa1 = *(const float4*)(xp + 36);
            xa2 = *(const float4*)(xp + 40);
            xa3 = *(const float4*)(xp + 44);
            const float* wp2 = wp + (size_t)32 * 192;
#pragma unroll
            for (int j = 0; j < 8; ++j) wr[j] = wp2[(size_t)j * 192];
        }
#pragma unroll
        for (int k = 0; k < 32; ++k) {
            float4 a0 = *(const float4*)&xsT[k][ty * 8];
            float4 a1 = *(const float4*)&xsT[k][ty * 8 + 4];
            float4 b4 = *(const float4*)&wsld[k][tx * 4];
#pragma unroll
            for (int cc = 0; cc < 4; ++cc) {
                const float bb = (cc == 0) ? b4.x : (cc == 1) ? b4.y : (cc == 2) ? b4.z : b4.w;
                acc[0][cc] = fmaf(a0.x, bb, acc[0][cc]);
                acc[1][cc] = fmaf(a0.y, bb, acc[1][cc]);
                acc[2][cc] = fmaf(a0.z, bb, acc[2][cc]);
                acc[3][cc] = fmaf(a0.w, bb, acc[3][cc]);
                acc[4][cc] = fmaf(a1.x, bb, acc[4][cc]);
                acc[5][cc] = fmaf(a1.y, bb, acc[5][cc]);
                acc[6][cc] = fmaf(a1.z, bb, acc[6][cc]);
                acc[7][cc] = fmaf(a1.w, bb, acc[7][cc]);
            }
        }
    }

    float* pbase = pq + (size_t)ks * 192 * 2048 + (size_t)cb * 2048 + i0;
#pragma unroll
    for (int cc = 0; cc < 4; ++cc) {
        float* dst = pbase + (size_t)(tx * 4 + cc) * 2048 + ty * 8;
        *(float4*)(dst)     = make_float4(acc[0][cc], acc[1][cc], acc[2][cc], acc[3][cc]);
        *(float4*)(dst + 4) = make_float4(acc[4][cc], acc[5][cc], acc[6][cc], acc[7][cc]);
    }
}

// sum 16 partials -> qsv (q|sk|v head-major). Scale already folded into wT.
__global__ __launch_bounds__(256) void qkv_reduce(const float* __restrict__ pq,
                                                  float* __restrict__ qsv) {
    const int idx = blockIdx.x * 256 + threadIdx.x;   // 98304 threads
    const int f = idx >> 9;                           // 0..191
    const int i = (idx & 511) * 4;
    const size_t S = (size_t)192 * 2048;
    const size_t o = (size_t)f * 2048 + i;
    float sx = 0.f, sy = 0.f, sz = 0.f, sw = 0.f;
#pragma unroll
    for (int s = 0; s < 16; ++s) {
        float4 a = *(const float4*)(pq + (size_t)s * S + o);
        sx += a.x; sy += a.y; sz += a.z; sw += a.w;
    }
    const int which = f >> 6;          // 0=q 1=sk 2=v
    const int h = f & 63;
    *(float4*)(qsv + (size_t)which * 131072 + (size_t)h * 2048 + i) =
        make_float4(sx, sy, sz, sw);
}

// attn: block = (h, p), p=0..15 handles row-blocks rb1=p and rb2=31-p.
// INSTRUMENTED: compute repeated `reps` times (idempotent; opaque q per rep).
__global__ __launch_bounds__(512) void attn_kernel(const float* __restrict__ qsv,
                                                   float* __restrict__ aws,
                                                   int reps) {
    __shared__ float ssk[2048];
    __shared__ float svv[2048];
    __shared__ float red[8][64][5];
    const int t = threadIdx.x;
    const int h = blockIdx.x & 63;
    const int p = blockIdx.x >> 6;          // 0..15
    const int lane = t & 63;
    const int c = t >> 6;                   // j-slice 0..7

    const int Alen = (p + 1) * 64;
    const int L    = (32 - p) * 64;
    const float* skp = qsv + 131072 + (size_t)h * 2048;
    const float* vp  = qsv + 262144 + (size_t)h * 2048;

    for (int idx = t * 4; idx < L; idx += 2048) {
        *(float4*)&ssk[idx] = *(const float4*)(skp + idx);
        *(float4*)&svv[idx] = *(const float4*)(vp + idx);
    }
    __syncthreads();

    const int i1 = Alen - 64 + lane;
    const int i2 = L - 64 + lane;
    const float qv1 = qsv[(size_t)h * 2048 + i1];
    const float qv2 = qsv[(size_t)h * 2048 + i2];

    const int gs = c * 264, ge = gs + 264;

    for (int r = 0; r < reps; ++r) {
        float qa = qv1, qb = qv2;
        asm volatile("" : "+v"(qa), "+v"(qb));   // opaque: no cross-rep CSE

        float dA[4] = {0.f, 0.f, 0.f, 0.f}, nA[4] = {0.f, 0.f, 0.f, 0.f};
        float dB[4] = {0.f, 0.f, 0.f, 0.f}, nB[4] = {0.f, 0.f, 0.f, 0.f};

        // ---- part A: rows rb1=p, j-range [gs, min(ge,Alen)) ----
        if (gs < Alen) {
            const int a1 = (ge < Alen) ? ge : Alen;
            const int d1 = Alen - 64;
            const int be = (a1 < d1) ? a1 : d1;
            for (int j = gs; j < be; j += 8) {
#pragma unroll
                for (int u = 0; u < 2; ++u) {
                    float4 s = *(const float4*)&ssk[j + 4 * u];
                    float4 v = *(const float4*)&svv[j + 4 * u];
                    float e0 = EXP2F(qa * s.x), e1 = EXP2F(qa * s.y);
                    float e2 = EXP2F(qa * s.z), e3 = EXP2F(qa * s.w);
                    dA[0] += e0; nA[0] = fmaf(e0, v.x, nA[0]);
                    dA[1] += e1; nA[1] = fmaf(e1, v.y, nA[1]);
                    dA[2] += e2; nA[2] = fmaf(e2, v.z, nA[2]);
                    dA[3] += e3; nA[3] = fmaf(e3, v.w, nA[3]);
                }
            }
            const int ms = (gs > d1) ? gs : d1;
            for (int j = ms; j < a1; j += 8) {
#pragma unroll
                for (int u = 0; u < 2; ++u) {
                    float4 s = *(const float4*)&ssk[j + 4 * u];
                    float4 v = *(const float4*)&svv[j + 4 * u];
                    const int jb = j + 4 * u;
                    float e0 = (jb     <= i1) ? EXP2F(qa * s.x) : 0.f;
                    float e1 = (jb + 1 <= i1) ? EXP2F(qa * s.y) : 0.f;
                    float e2 = (jb + 2 <= i1) ? EXP2F(qa * s.z) : 0.f;
                    float e3 = (jb + 3 <= i1) ? EXP2F(qa * s.w) : 0.f;
                    dA[0] += e0; nA[0] = fmaf(e0, v.x, nA[0]);
                    dA[1] += e1; nA[1] = fmaf(e1, v.y, nA[1]);
                    dA[2] += e2; nA[2] = fmaf(e2, v.z, nA[2]);
                    dA[3] += e3; nA[3] = fmaf(e3, v.w, nA[3]);
                }
            }
        }

        // ---- part B: rows rb2=31-p, j-range [max(gs,Alen)-Alen, ge-Alen) ----
        if (ge > Alen) {
            const int b0 = ((gs > Alen) ? gs : Alen) - Alen;
            const int b1 = ge - Alen;
            const int d2 = L - 64;
            const int be = (b1 < d2) ? b1 : d2;
            for (int j = b0; j < be; j += 8) {
#pragma unroll
                for (int u = 0; u < 2; ++u) {
                    float4 s = *(const float4*)&ssk[j + 4 * u];
                    float4 v = *(const float4*)&svv[j + 4 * u];
                    float e0 = EXP2F(qb * s.x), e1 = EXP2F(qb * s.y);
                    float e2 = EXP2F(qb * s.z), e3 = EXP2F(qb * s.w);
                    dB[0] += e0; nB[0] = fmaf(e0, v.x, nB[0]);
                    dB[1] += e1; nB[1] = fmaf(e1, v.y, nB[1]);
                    dB[2] += e2; nB[2] = fmaf(e2, v.z, nB[2]);
                    dB[3] += e3; nB[3] = fmaf(e3, v.w, nB[3]);
                }
            }
            const int ms = (b0 > d2) ? b0 : d2;
            for (int j = ms; j < b1; j += 8) {
#pragma unroll
                for (int u = 0; u < 2; ++u) {
                    float4 s = *(const float4*)&ssk[j + 4 * u];
                    float4 v = *(const float4*)&svv[j + 4 * u];
                    const int jb = j + 4 * u;
                    float e0 = (jb     <= i2) ? EXP2F(qb * s.x) : 0.f;
                    float e1 = (jb + 1 <= i2) ? EXP2F(qb * s.y) : 0.f;
                    float e2 = (jb + 2 <= i2) ? EXP2F(qb * s.z) : 0.f;
                    float e3 = (jb + 3 <= i2) ? EXP2F(qb * s.w) : 0.f;
                    dB[0] += e0; nB[0] = fmaf(e0, v.x, nB[0]);
                    dB[1] += e1; nB[1] = fmaf(e1, v.y, nB[1]);
                    dB[2] += e2; nB[2] = fmaf(e2, v.z, nB[2]);
                    dB[3] += e3; nB[3] = fmaf(e3, v.w, nB[3]);
                }
            }
        }

        red[c][lane][0] = (nA[0] + nA[1]) + (nA[2] + nA[3]);
        red[c][lane][1] = (dA[0] + dA[1]) + (dA[2] + dA[3]);
        red[c][lane][2] = (nB[0] + nB[1]) + (nB[2] + nB[3]);
        red[c][lane][3] = (dB[0] + dB[1]) + (dB[2] + dB[3]);
        __syncthreads();

        if (t < 64) {
            float n = 0.f, d = 0.f;
#pragma unroll
            for (int s = 0; s < 8; ++s) { n += red[s][t][0]; d += red[s][t][1]; }
            aws[(size_t)h * 2048 + (Alen - 64 + t)] = n / d;
        } else if (t < 128) {
            const int l = t - 64;
            float n = 0.f, d = 0.f;
#pragma unroll
            for (int s = 0; s < 8; ++s) { n += red[s][l][2]; d += red[s][l][3]; }
            aws[(size_t)h * 2048 + (L - 64 + l)] = n / d;
        }
        __syncthreads();   // red[] reused next rep
    }
}

// proj: out[i][c] = sum_h aws[h][i] * wOutT[h][c].
// grid 2048 = 256 i-tiles(8 rows) x 8 c-tiles(128 cols); block 256.
__global__ __launch_bounds__(256) void proj_kernel(const float* __restrict__ aws,
                                                   const float* __restrict__ wOutT,
                                                   float* __restrict__ out) {
    __shared__ float ast[64][8];
    const int t = threadIdx.x;
    const int i0 = (blockIdx.x >> 3) * 8;
    const int c0 = (blockIdx.x & 7) * 128;

    for (int s = t; s < 512; s += 256) {
        const int hh = s >> 3, ii = s & 7;
        ast[hh][ii] = aws[(size_t)hh * 2048 + i0 + ii];
    }
    __syncthreads();

    const int rg = t >> 5;      // row 0..7
    const int cg = t & 31;      // col-quad 0..31
    const float* wp = wOutT + c0 + cg * 4;
    float a0 = 0.f, a1 = 0.f, a2 = 0.f, a3 = 0.f;
#pragma unroll 8
    for (int hc = 0; hc < 64; ++hc) {
        float4 w4 = *(const float4*)(wp + (size_t)hc * 1024);
        float a = ast[hc][rg];
        a0 = fmaf(a, w4.x, a0);
        a1 = fmaf(a, w4.y, a1);
        a2 = fmaf(a, w4.z, a2);
        a3 = fmaf(a, w4.w, a3);
    }
    *(float4*)(out + (size_t)(i0 + rg) * 1024 + c0 + cg * 4) = make_float4(a0, a1, a2, a3);
}

extern "C" void kernel_launch(void* const* d_in, const int* in_sizes, int n_in,
                              void* d_out, int out_size, void* d_ws, size_t ws_size,
                              hipStream_t stream) {
    const float* x     = (const float*)d_in[0];   // [1,2048,1024]
    const float* w_qkv = (const float*)d_in[1];   // [192,1024]
    const float* w_out = (const float*)d_in[2];   // [1024,64]
    float* out = (float*)d_out;                   // [1,2048,1024]

    float* ws    = (float*)d_ws;
    float* wT    = ws;                 // 196608
    float* wOutT = wT + 196608;        // 65536
    float* qsv   = wOutT + 65536;      // 3*64*2048 = 393216  (q | sk | v)
    float* aws   = qsv + 393216;       // 131072
    float* pq    = aws + 131072;       // 16*192*2048 = 6291456

    prep_kernel<<<dim3(64), dim3(256), 0, stream>>>(w_qkv, w_out, wT, wOutT);
    qkv_gemm<<<dim3(768), dim3(256), 0, stream>>>(x, wT, pq);
    qkv_reduce<<<dim3(384), dim3(256), 0, stream>>>(pq, qsv);
    attn_kernel<<<dim3(1024), dim3(512), 0, stream>>>(qsv, aws, 4);
    proj_kernel<<<dim3(2048), dim3(256), 0, stream>>>(aws, wOutT, out);
}